// Round 10
// baseline (1220.112 us; speedup 1.0000x reference)
//
#include <hip/hip_runtime.h>
#include <math.h>

#define BB 32
#define N_IN 8192
#define M 819
#define M2 1638
#define KNN 16
#define RPB 32      // rows per knn block
#define NCH 8       // candidate chunks per row
#define CHLEN 206   // chunks: 206x7 + 196

// ---------------- Threefry-2x32, PARTITIONABLE layout (validated round 5) ----------------
__device__ __forceinline__ unsigned tf_rotl(unsigned x, int r){ return (x<<r)|(x>>(32-r)); }

__device__ __forceinline__ float erfinv_xla_f32(float x){
  float w = -log1pf(-__fmul_rn(x,x));
  float p;
  if (w < 5.0f) {
    w = __fsub_rn(w, 2.5f);
    p = 2.81022636e-08f;
    p = fmaf(p, w, 3.43273939e-07f);
    p = fmaf(p, w, -3.5233877e-06f);
    p = fmaf(p, w, -4.39150654e-06f);
    p = fmaf(p, w, 0.00021858087f);
    p = fmaf(p, w, -0.00125372503f);
    p = fmaf(p, w, -0.00417768164f);
    p = fmaf(p, w, 0.246640727f);
    p = fmaf(p, w, 1.50140941f);
  } else {
    w = __fsub_rn(sqrtf(w), 3.0f);
    p = -0.000200214257f;
    p = fmaf(p, w, 0.000100950558f);
    p = fmaf(p, w, 0.00134934322f);
    p = fmaf(p, w, -0.00367342844f);
    p = fmaf(p, w, 0.00573950773f);
    p = fmaf(p, w, -0.0076224613f);
    p = fmaf(p, w, 0.00943887047f);
    p = fmaf(p, w, 1.00167406f);
    p = fmaf(p, w, 2.83297682f);
  }
  return __fmul_rn(p, x);
}

__device__ __forceinline__ float noise_at(unsigned e){
  unsigned x0 = 0u, x1 = e;
  const unsigned k0 = 0u, k1 = 42u, k2 = 0u ^ 42u ^ 0x1BD11BDAu;
  x0 += k0; x1 += k1;
#define TFR(r) { x0 += x1; x1 = tf_rotl(x1, r); x1 ^= x0; }
  TFR(13) TFR(15) TFR(26) TFR(6)   x0 += k1; x1 += k2 + 1u;
  TFR(17) TFR(29) TFR(16) TFR(24)  x0 += k2; x1 += k0 + 2u;
  TFR(13) TFR(15) TFR(26) TFR(6)   x0 += k0; x1 += k1 + 3u;
  TFR(17) TFR(29) TFR(16) TFR(24)  x0 += k1; x1 += k2 + 4u;
  TFR(13) TFR(15) TFR(26) TFR(6)   x0 += k2; x1 += k0 + 5u;
#undef TFR
  unsigned bits = x0 ^ x1;
  float f = __uint_as_float((bits >> 9) | 0x3f800000u) - 1.0f;
  const float lo = -0.99999994f;
  float u = fmaf(f, 2.0f, lo);
  u = fmaxf(lo, u);
  float z = erfinv_xla_f32(u);
  float nrm = __fmul_rn(__uint_as_float(0x3FB504F3u), z);
  return __fmul_rn(nrm, 0.01f);
}

// f32 max step via DPP (VALU domain): 1 dpp-mov + 1 v_max
__device__ __forceinline__ float dpp_max_f32(float v, const int ctrl){
  int iv = __float_as_int(v);
  int sv;
  switch (ctrl) {
    case 0x111: sv = __builtin_amdgcn_update_dpp(iv, iv, 0x111, 0xF, 0xF, false); break;
    case 0x112: sv = __builtin_amdgcn_update_dpp(iv, iv, 0x112, 0xF, 0xF, false); break;
    case 0x114: sv = __builtin_amdgcn_update_dpp(iv, iv, 0x114, 0xF, 0xF, false); break;
    case 0x118: sv = __builtin_amdgcn_update_dpp(iv, iv, 0x118, 0xF, 0xF, false); break;
    case 0x142: sv = __builtin_amdgcn_update_dpp(iv, iv, 0x142, 0xF, 0xF, false); break;
    default:    sv = __builtin_amdgcn_update_dpp(iv, iv, 0x143, 0xF, 0xF, false); break;
  }
  return fmaxf(v, __int_as_float(sv));
}

// ---------------- Kernel 1: FPS — value-only DPP max + equality recovery ----------------
__global__ __launch_bounds__(512, 1) void fps_kernel(const float* __restrict__ pin,
                                                     float* __restrict__ ptsO){
  const int b = blockIdx.x;
  const int t = threadIdx.x;
  const float* P = pin + (size_t)b * N_IN * 3;

  __shared__ float s_x[N_IN], s_y[N_IN], s_z[N_IN];
  __shared__ int   s_sel[M];
  __shared__ float s_wmax[8];
  __shared__ int   s_best[2];

  for (int i = t; i < N_IN; i += 512) {
    s_x[i] = P[i*3+0]; s_y[i] = P[i*3+1]; s_z[i] = P[i*3+2];
  }
  float px[16], py[16], pz[16], mind[16];
#pragma unroll
  for (int k = 0; k < 16; ++k) {
    int p = t + (k<<9);
    px[k] = P[p*3+0]; py[k] = P[p*3+1]; pz[k] = P[p*3+2];
    mind[k] = 1e10f;
  }
  if (t == 0) { s_sel[0] = 0; s_best[0] = 0x7fffffff; s_best[1] = 0x7fffffff; }
  float lx = P[0], ly = P[1], lz = P[2];
  __syncthreads();

  for (int i = 1; i < M; ++i) {
    const int par = i & 1;
    float tmax = -1.0f;
#pragma unroll
    for (int k = 0; k < 16; ++k) {
      float dx = __fsub_rn(px[k], lx);
      float dy = __fsub_rn(py[k], ly);
      float dz = __fsub_rn(pz[k], lz);
      float d  = __fadd_rn(__fadd_rn(__fmul_rn(dx,dx), __fmul_rn(dy,dy)), __fmul_rn(dz,dz));
      float m  = fminf(mind[k], d);
      mind[k] = m;
      tmax = fmaxf(tmax, m);          // value only — no per-point index tracking
    }
    // wave-level f32 max (6 DPP steps, lane63 holds wave max)
    float wmax = tmax;
    wmax = dpp_max_f32(wmax, 0x111);
    wmax = dpp_max_f32(wmax, 0x112);
    wmax = dpp_max_f32(wmax, 0x114);
    wmax = dpp_max_f32(wmax, 0x118);
    wmax = dpp_max_f32(wmax, 0x142);
    wmax = dpp_max_f32(wmax, 0x143);
    if ((t & 63) == 63) s_wmax[t>>6] = wmax;
    __syncthreads();                   // barrier A: s_wmax published
    if (t == 0) s_best[par ^ 1] = 0x7fffffff;   // reset NEXT iter's slot (this iter uses [par])
    float gmax = s_wmax[0];
#pragma unroll
    for (int w2 = 1; w2 < 8; ++w2) gmax = fmaxf(gmax, s_wmax[w2]);
    if (tmax == gmax) {                // exact bit equality: v_max returns operand bits
      int flat = 0x7fffffff;
#pragma unroll
      for (int k = 15; k >= 0; --k)    // descending: last write = smallest k
        if (mind[k] == gmax) flat = t + (k<<9);
      atomicMin(&s_best[par], flat);   // min over (t,k) of t+512k = np.argmax first-max index
    }
    __syncthreads();                   // barrier B: s_best final
    int bsel = s_best[par];
    if (t == 0) s_sel[i] = bsel;
    lx = s_x[bsel]; ly = s_y[bsel]; lz = s_z[bsel];
  }
  __syncthreads();

  for (int j = t; j < M; j += 512) {
    int sj = s_sel[j];
    float x = s_x[sj], y = s_y[sj], z = s_z[sj];
    float* o0 = ptsO + ((size_t)b*M2 + j)*3;
    float* o1 = o0 + (size_t)M*3;
    o0[0]=x; o0[1]=y; o0[2]=z;
    unsigned e0 = (unsigned)(b*M + j) * 3u;
    o1[0] = __fadd_rn(x, noise_at(e0+0u));
    o1[1] = __fadd_rn(y, noise_at(e0+1u));
    o1[2] = __fadd_rn(z, noise_at(e0+2u));
  }
}

// ---------------- math helpers ----------------
__device__ __forceinline__ float gelu_f(float x){
  return x * (erff(x / 1.41421356237f) + 1.0f) * 0.5f;
}
__device__ __forceinline__ float softplus_f(float x){
  return fmaxf(x, 0.0f) + log1pf(expf(-fabsf(x)));
}
__device__ __forceinline__ void eig3_sym(double a00,double a01,double a02,double a11,double a12,double a22,
                                         double& s0o, double& s1o, double& s2o){
  double p1 = a01*a01 + a02*a02 + a12*a12;
  double q  = (a00+a11+a22)/3.0;
  double b00=a00-q, b11=a11-q, b22=a22-q;
  double p2 = b00*b00+b11*b11+b22*b22 + 2.0*p1;
  double e0,e1,e2;
  if (p2 <= 0.0) { e0=e1=e2=q; }
  else {
    double p  = sqrt(p2/6.0);
    double ip = 1.0/p;
    double c00=b00*ip, c01=a01*ip, c02=a02*ip, c11=b11*ip, c12=a12*ip, c22=b22*ip;
    double detB = c00*(c11*c22-c12*c12) - c01*(c01*c22-c12*c02) + c02*(c01*c12-c11*c02);
    double r = 0.5*detB;
    r = fmin(1.0, fmax(-1.0, r));
    double phi = acos(r)/3.0;
    e0 = q + 2.0*p*cos(phi);
    e2 = q + 2.0*p*cos(phi + 2.0943951023931953);
    e1 = 3.0*q - e0 - e2;
  }
  double s0 = fabs(e0), s1 = fabs(e1), s2 = fabs(e2), t;
  if (s0 < s1){t=s0;s0=s1;s1=t;}
  if (s1 < s2){t=s1;s1=s2;s2=t;}
  if (s0 < s1){t=s0;s0=s1;s1=t;}
  s0o=s0; s1o=s1; s2o=s2;
}

// stable top-17 insert (d2 asc, scan order = idx asc on ties), shared-compare form
__device__ __forceinline__ void ins17(float d2, int j, float bd[17], int bix[17]){
  bool c[17];
#pragma unroll
  for (int k = 0; k < 17; ++k) c[k] = d2 < bd[k];
#pragma unroll
  for (int k = 16; k > 0; --k) {
    bd[k]  = c[k-1] ? bd[k-1] : (c[k] ? d2 : bd[k]);
    bix[k] = c[k-1] ? bix[k-1] : (c[k] ? j : bix[k]);
  }
  if (c[0]) { bd[0] = d2; bix[0] = j; }
}

// monotone map f32 -> u32 (order-preserving incl. negatives)
__device__ __forceinline__ unsigned fmono(float f){
  unsigned u = __float_as_uint(f);
  return (u & 0x80000000u) ? ~u : (u | 0x80000000u);
}

// ---------------- Kernel 2: chunked KNN top-17 (8 chunks x 32 rows) + u64 8-way merge ----------------
__global__ __launch_bounds__(256) void knn_select(const float* __restrict__ ptsG,
                                                  float* __restrict__ RO){
  const int b = blockIdx.x, tid = threadIdx.x;

  __shared__ __align__(16) unsigned char smem[35840];
  float4* sp = (float4*)smem;                                    // phase A: 1638*16 = 26208 B

  for (int i = tid; i < M2; i += 256) {
    const float* p = ptsG + ((size_t)b*M2 + i)*3;
    float x=p[0], y=p[1], z=p[2];
    float sq = __fadd_rn(__fadd_rn(__fmul_rn(x,x),__fmul_rn(y,y)),__fmul_rn(z,z));
    sp[i] = make_float4(x,y,z,sq);
  }
  __syncthreads();

  const int rl    = tid >> 3;
  const int chunk = tid & 7;
  const int row   = blockIdx.y*RPB + rl;
  const bool valid = row < M2;

  float4 me = sp[valid ? row : 0];
  const float px = me.x, py = me.y, pz = me.z, psq = me.w;

  float bd[17]; int bix[17];
#pragma unroll
  for (int k=0;k<17;++k){ bd[k]=3.4e38f; bix[k]=0x7fffffff; }

  const int j0 = chunk*CHLEN;
  const int j1 = (j0 + CHLEN < M2) ? (j0 + CHLEN) : M2;
  int j = j0;
  for (; j + 3 < j1; j += 4) {
    float4 qa = sp[j];
    float4 qb = sp[j+1];
    float4 qc = sp[j+2];
    float4 qd = sp[j+3];
    float dota = fmaf(pz, qa.z, fmaf(py, qa.y, __fmul_rn(px, qa.x)));
    float d2a  = __fsub_rn(__fadd_rn(psq, qa.w), __fmul_rn(2.0f, dota));
    float dotb = fmaf(pz, qb.z, fmaf(py, qb.y, __fmul_rn(px, qb.x)));
    float d2b  = __fsub_rn(__fadd_rn(psq, qb.w), __fmul_rn(2.0f, dotb));
    float dotc = fmaf(pz, qc.z, fmaf(py, qc.y, __fmul_rn(px, qc.x)));
    float d2c  = __fsub_rn(__fadd_rn(psq, qc.w), __fmul_rn(2.0f, dotc));
    float dotd = fmaf(pz, qd.z, fmaf(py, qd.y, __fmul_rn(px, qd.x)));
    float d2d  = __fsub_rn(__fadd_rn(psq, qd.w), __fmul_rn(2.0f, dotd));
    if (fminf(fminf(d2a, d2b), fminf(d2c, d2d)) < bd[16]) {
      if (d2a < bd[16]) ins17(d2a, j,   bd, bix);
      if (d2b < bd[16]) ins17(d2b, j+1, bd, bix);
      if (d2c < bd[16]) ins17(d2c, j+2, bd, bix);
      if (d2d < bd[16]) ins17(d2d, j+3, bd, bix);
    }
  }
  for (; j < j1; j += 2) {
    float4 qa = sp[j];
    float4 qb = sp[j+1];
    float dota = fmaf(pz, qa.z, fmaf(py, qa.y, __fmul_rn(px, qa.x)));
    float d2a  = __fsub_rn(__fadd_rn(psq, qa.w), __fmul_rn(2.0f, dota));
    float dotb = fmaf(pz, qb.z, fmaf(py, qb.y, __fmul_rn(px, qb.x)));
    float d2b  = __fsub_rn(__fadd_rn(psq, qb.w), __fmul_rn(2.0f, dotb));
    if (fminf(d2a, d2b) < bd[16]) {
      if (d2a < bd[16]) ins17(d2a, j,   bd, bix);
      if (d2b < bd[16]) ins17(d2b, j+1, bd, bix);
    }
  }
  __syncthreads();   // sp dead; reuse smem for per-chunk lists

  unsigned long long* s_kid = (unsigned long long*)smem;         // 32*8*17*8 = 34816
  unsigned short*     s_nbr = (unsigned short*)(smem + 34816);   // 32*16*2   =  1024

  if (valid) {
    const int basel = (rl*NCH + chunk)*17;
#pragma unroll
    for (int k = 0; k < 17; ++k)
      s_kid[basel + k] = ((unsigned long long)fmono(bd[k]) << 32) | (unsigned)bix[k];
  }
  __syncthreads();

  if (chunk == 0 && valid) {
    int h0=0,h1=0,h2=0,h3=0,h4=0,h5=0,h6=0,h7=0;
    const int lb = rl*NCH*17;
    for (int e = 0; e < 17; ++e) {
      unsigned long long k0 = s_kid[lb        + h0];
      unsigned long long k1 = s_kid[lb + 17   + h1];
      unsigned long long k2 = s_kid[lb + 34   + h2];
      unsigned long long k3 = s_kid[lb + 51   + h3];
      unsigned long long k4 = s_kid[lb + 68   + h4];
      unsigned long long k5 = s_kid[lb + 85   + h5];
      unsigned long long k6 = s_kid[lb + 102  + h6];
      unsigned long long k7 = s_kid[lb + 119  + h7];
      unsigned long long bk = k0; int bc = 0;
      if (k1 < bk) { bk = k1; bc = 1; }
      if (k2 < bk) { bk = k2; bc = 2; }
      if (k3 < bk) { bk = k3; bc = 3; }
      if (k4 < bk) { bk = k4; bc = 4; }
      if (k5 < bk) { bk = k5; bc = 5; }
      if (k6 < bk) { bk = k6; bc = 6; }
      if (k7 < bk) { bk = k7; bc = 7; }
      h0 += (bc==0); h1 += (bc==1); h2 += (bc==2); h3 += (bc==3);
      h4 += (bc==4); h5 += (bc==5); h6 += (bc==6); h7 += (bc==7);
      if (e > 0) s_nbr[rl*16 + (e-1)] = (unsigned short)(bk & 0xffffu);  // entry 0 = self, dropped
    }
    uint* kout = (uint*)(RO + ((size_t)b*M2 + row)*9);
#pragma unroll
    for (int k = 0; k < 8; ++k)
      kout[k] = (uint)s_nbr[rl*16 + 2*k] | ((uint)s_nbr[rl*16 + 2*k + 1] << 16);
  }
}

// ---------------- Kernel 3: per-row geometry (validated) ----------------
__global__ __launch_bounds__(256) void geom_kernel(
    const float* __restrict__ ptsG,
    const float* __restrict__ rw1, const float* __restrict__ rb1,
    const float* __restrict__ rw2, const float* __restrict__ rb2,
    const float* __restrict__ sw1, const float* __restrict__ sb1,
    const float* __restrict__ sw2, const float* __restrict__ sb2,
    float* __restrict__ covO, float* __restrict__ RO, float* __restrict__ scO,
    float* __restrict__ linW, float* __restrict__ denW)
{
  const int tid = threadIdx.x;
  __shared__ float w_rw1[192], w_rb1[64], w_rw2[192], w_rb2[3];
  __shared__ float w_sw1[192], w_sb1[64], w_sw2[192], w_sb2[3];
  if (tid < 192) { w_rw1[tid]=rw1[tid]; w_rw2[tid]=rw2[tid]; w_sw1[tid]=sw1[tid]; w_sw2[tid]=sw2[tid]; }
  if (tid < 64) { w_rb1[tid]=rb1[tid]; w_sb1[tid]=sb1[tid]; }
  if (tid < 3)  { w_rb2[tid]=rb2[tid]; w_sb2[tid]=sb2[tid]; }
  __syncthreads();

  const int gid = blockIdx.x*256 + tid;
  if (gid >= BB*M2) return;
  const int b = gid / M2;
  const size_t base = (size_t)gid;

  const uint* kin = (const uint*)(RO + base*9);
  uint kw[8];
#pragma unroll
  for (int k = 0; k < 8; ++k) kw[k] = kin[k];
  asm volatile("" ::: "memory");

  int nidx[16];
#pragma unroll
  for (int k = 0; k < 8; ++k) { nidx[2*k] = (int)(kw[k] & 0xffffu); nidx[2*k+1] = (int)(kw[k] >> 16); }

  const float* meP = ptsG + base*3;
  const float px = meP[0], py = meP[1], pz = meP[2];
  const double pxd = (double)px, pyd = (double)py, pzd = (double)pz;

  float nx[16], ny[16], nz[16];
#pragma unroll
  for (int k = 0; k < 16; ++k) {
    const float* np = ptsG + ((size_t)b*M2 + nidx[k])*3;
    nx[k] = np[0]; ny[k] = np[1]; nz[k] = np[2];
  }

  float wcx=0.f, wcy=0.f, wcz=0.f;
#pragma unroll
  for (int k=0;k<16;++k){ wcx += nx[k]; wcy += ny[k]; wcz += nz[k]; }
  wcx *= 0.0625f; wcy *= 0.0625f; wcz *= 0.0625f;

  float aa0=0.f, aa1=0.f, aa2=0.f;
  for (int j = 0; j < 64; ++j) {
    float hp = __fadd_rn(__fadd_rn(__fadd_rn(__fmul_rn(wcx,w_rw1[j]), __fmul_rn(wcy,w_rw1[64+j])),
                                   __fmul_rn(wcz,w_rw1[128+j])), w_rb1[j]);
    float h = gelu_f(hp);
    aa0 += h*w_rw2[j*3+0]; aa1 += h*w_rw2[j*3+1]; aa2 += h*w_rw2[j*3+2];
  }
  aa0 += w_rb2[0]; aa1 += w_rb2[1]; aa2 += w_rb2[2];

  float angle = sqrtf(__fadd_rn(__fadd_rn(__fmul_rn(aa0,aa0),__fmul_rn(aa1,aa1)),__fmul_rn(aa2,aa2)));
  bool  tsml  = angle < 1e-4f;
  float sang  = tsml ? 0.0f : fminf(angle, 3.14f);
  float ax, ay, az;
  if (tsml) { ax=1.0f; ay=0.0f; az=0.0f; }
  else { float inv = angle + 1e-6f; ax = aa0/inv; ay = aa1/inv; az = aa2/inv; }

  float v0 = ax*sang, v1 = ay*sang, v2 = az*sang;
  float ang2 = sqrtf(__fadd_rn(__fadd_rn(__fmul_rn(v0,v0),__fmul_rn(v1,v1)),__fmul_rn(v2,v2)));
  float inv2 = ang2 + 1e-6f;
  float x = v0/inv2, y = v1/inv2, z = v2/inv2;
  float ca = cosf(ang2), sa = sinf(ang2), Cc = 1.0f - ca;
  float R00 = ca + x*x*Cc,   R01 = x*y*Cc - z*sa, R02 = x*z*Cc + y*sa;
  float R10 = y*x*Cc + z*sa, R11 = ca + y*y*Cc,   R12 = y*z*Cc - x*sa;
  float R20 = z*x*Cc - y*sa, R21 = z*y*Cc + x*sa, R22 = ca + z*z*Cc;

  float sp0=0.f, sp1=0.f, sp2=0.f;
  for (int j = 0; j < 64; ++j) {
    float hp = __fadd_rn(__fadd_rn(__fadd_rn(__fmul_rn(px,w_sw1[j]), __fmul_rn(py,w_sw1[64+j])),
                                   __fmul_rn(pz,w_sw1[128+j])), w_sb1[j]);
    float h = gelu_f(hp);
    sp0 += h*w_sw2[j*3+0]; sp1 += h*w_sw2[j*3+1]; sp2 += h*w_sw2[j*3+2];
  }
  sp0 += w_sb2[0]; sp1 += w_sb2[1]; sp2 += w_sb2[2];
  float sc0 = fminf(fmaxf(softplus_f(sp0), 0.01f), 0.5f);
  float sc1 = fminf(fmaxf(softplus_f(sp1), 0.01f), 0.5f);
  float sc2 = fminf(fmaxf(softplus_f(sp2), 0.01f), 0.5f);

  float s2x = sc0*sc0, s2y = sc1*sc1, s2z = sc2*sc2;
  float T00 = R00*s2x, T01 = R01*s2y, T02 = R02*s2z;
  float T10 = R10*s2x, T11 = R11*s2y, T12 = R12*s2z;
  float T20 = R20*s2x, T21 = R21*s2y, T22 = R22*s2z;
  float C00 = T00*R00 + T01*R01 + T02*R02;
  float C01 = T00*R10 + T01*R11 + T02*R12;
  float C02 = T00*R20 + T01*R21 + T02*R22;
  float C10 = T10*R00 + T11*R01 + T12*R02;
  float C11 = T10*R10 + T11*R11 + T12*R12;
  float C12 = T10*R20 + T11*R21 + T12*R22;
  float C20 = T20*R00 + T21*R01 + T22*R02;
  float C21 = T20*R10 + T21*R11 + T22*R12;
  float C22 = T20*R20 + T21*R21 + T22*R22;

  double n00=0.,n01=0.,n02=0.,n11=0.,n12=0.,n22=0.;
  int cnt = 0;
  const double R2 = 0.1*0.1;
#pragma unroll
  for (int k=0;k<16;++k){
    double cx = (double)nx[k] - pxd;
    double cy = (double)ny[k] - pyd;
    double cz = (double)nz[k] - pzd;
    n00 += cx*cx; n01 += cx*cy; n02 += cx*cz;
    n11 += cy*cy; n12 += cy*cz; n22 += cz*cz;
    double dd = cx*cx + cy*cy + cz*cz;
    if (dd < R2) cnt++;
  }
  const double inv15 = 15.0 + 1e-6;
  n00/=inv15; n01/=inv15; n02/=inv15; n11/=inv15; n12/=inv15; n22/=inv15;

  double sv0, sv1, sv2;
  eig3_sym(n00,n01,n02,n11,n12,n22, sv0, sv1, sv2);
  float lin = (float)(sv0 / (sv1 + sv2 + 1e-6));
  float den = (float)cnt / 16.0f;

  float* cO = covO + base*9;
  cO[0]=C00; cO[1]=C01; cO[2]=C02; cO[3]=C10; cO[4]=C11; cO[5]=C12; cO[6]=C20; cO[7]=C21; cO[8]=C22;
  float* rO = RO + base*9;
  rO[0]=R00; rO[1]=R01; rO[2]=R02; rO[3]=R10; rO[4]=R11; rO[5]=R12; rO[6]=R20; rO[7]=R21; rO[8]=R22;
  float* sO = scO + base*3;
  sO[0]=sc0; sO[1]=sc1; sO[2]=sc2;
  linW[base] = lin;
  denW[base] = den;
}

// ---------------- Kernel 4: per-batch min/max ----------------
__global__ __launch_bounds__(256) void minmax_k(const float* __restrict__ linW,
                                                const float* __restrict__ denW,
                                                float* __restrict__ mmW){
  const int b = blockIdx.x, t = threadIdx.x;
  float lmin=3.4e38f, lmax=-3.4e38f, dmin=3.4e38f, dmax=-3.4e38f;
  for (int i = t; i < M2; i += 256) {
    float l = linW[b*M2+i], d = denW[b*M2+i];
    lmin=fminf(lmin,l); lmax=fmaxf(lmax,l);
    dmin=fminf(dmin,d); dmax=fmaxf(dmax,d);
  }
#pragma unroll
  for (int off = 32; off > 0; off >>= 1) {
    lmin=fminf(lmin,__shfl_down(lmin,(unsigned)off));
    lmax=fmaxf(lmax,__shfl_down(lmax,(unsigned)off));
    dmin=fminf(dmin,__shfl_down(dmin,(unsigned)off));
    dmax=fmaxf(dmax,__shfl_down(dmax,(unsigned)off));
  }
  __shared__ float s[4][4];
  int w = t >> 6;
  if ((t & 63) == 0) { s[w][0]=lmin; s[w][1]=lmax; s[w][2]=dmin; s[w][3]=dmax; }
  __syncthreads();
  if (t == 0) {
    for (int i = 1; i < 4; ++i) {
      s[0][0]=fminf(s[0][0],s[i][0]); s[0][1]=fmaxf(s[0][1],s[i][1]);
      s[0][2]=fminf(s[0][2],s[i][2]); s[0][3]=fmaxf(s[0][3],s[i][3]);
    }
    mmW[b*4+0]=s[0][0]; mmW[b*4+1]=s[0][1]; mmW[b*4+2]=s[0][2]; mmW[b*4+3]=s[0][3];
  }
}

// ---------------- Kernel 5: opacity ----------------
__global__ void opacity_k(const float* __restrict__ linW, const float* __restrict__ denW,
                          const float* __restrict__ mmW, float* __restrict__ opO){
  int gid = blockIdx.x*blockDim.x + threadIdx.x;
  if (gid >= BB*M2) return;
  int b = gid / M2;
  float lmin=mmW[b*4+0], lmax=mmW[b*4+1], dmin=mmW[b*4+2], dmax=mmW[b*4+3];
  float nl = (linW[gid]-lmin) / ((lmax-lmin) + 1e-6f);
  float nd = (denW[gid]-dmin) / ((dmax-dmin) + 1e-6f);
  float comb = nl * powf(nd, 0.45f);
  opO[gid] = fminf(fmaxf(comb, 0.05f), 0.95f);
}

// ---------------- launch ----------------
extern "C" void kernel_launch(void* const* d_in, const int* in_sizes, int n_in,
                              void* d_out, int out_size, void* d_ws, size_t ws_size,
                              hipStream_t stream) {
  const float* pin = (const float*)d_in[0];
  const float* rw1 = (const float*)d_in[1];
  const float* rb1 = (const float*)d_in[2];
  const float* rw2 = (const float*)d_in[3];
  const float* rb2 = (const float*)d_in[4];
  const float* sw1 = (const float*)d_in[5];
  const float* sb1 = (const float*)d_in[6];
  const float* sw2 = (const float*)d_in[7];
  const float* sb2 = (const float*)d_in[8];

  float* out  = (float*)d_out;
  float* ptsO = out;                                  // B*M2*3
  float* covO = ptsO + (size_t)BB*M2*3;               // B*M2*9
  float* opO  = covO + (size_t)BB*M2*9;               // B*M2
  float* RO   = opO  + (size_t)BB*M2;                 // B*M2*9
  float* scO  = RO   + (size_t)BB*M2*9;               // B*M2*3

  float* linW = (float*)d_ws + (size_t)BB*M;          // B*M2
  float* denW = linW + (size_t)BB*M2;                 // B*M2
  float* mmW  = denW + (size_t)BB*M2;                 // B*4

  fps_kernel<<<BB, 512, 0, stream>>>(pin, ptsO);
  dim3 g2(BB, (M2 + RPB - 1)/RPB);
  knn_select<<<g2, 256, 0, stream>>>(ptsO, RO);
  geom_kernel<<<(BB*M2 + 255)/256, 256, 0, stream>>>(ptsO, rw1, rb1, rw2, rb2, sw1, sb1, sw2, sb2,
                                                     covO, RO, scO, linW, denW);
  minmax_k<<<BB, 256, 0, stream>>>(linW, denW, mmW);
  opacity_k<<<(BB*M2 + 255)/256, 256, 0, stream>>>(linW, denW, mmW, opO);
}

// Round 12
// 1201.423 us; speedup vs baseline: 1.0156x; 1.0156x over previous
//
#include <hip/hip_runtime.h>
#include <math.h>

#define BB 32
#define N_IN 8192
#define M 819
#define M2 1638
#define KNN 16
#define RPB 32      // rows per knn block
#define NCH 8       // candidate chunks per row
#define CHLEN 206   // chunks: 206x7 + 196

// ---------------- Threefry-2x32, PARTITIONABLE layout (validated round 5) ----------------
__device__ __forceinline__ unsigned tf_rotl(unsigned x, int r){ return (x<<r)|(x>>(32-r)); }

__device__ __forceinline__ float erfinv_xla_f32(float x){
  float w = -log1pf(-__fmul_rn(x,x));
  float p;
  if (w < 5.0f) {
    w = __fsub_rn(w, 2.5f);
    p = 2.81022636e-08f;
    p = fmaf(p, w, 3.43273939e-07f);
    p = fmaf(p, w, -3.5233877e-06f);
    p = fmaf(p, w, -4.39150654e-06f);
    p = fmaf(p, w, 0.00021858087f);
    p = fmaf(p, w, -0.00125372503f);
    p = fmaf(p, w, -0.00417768164f);
    p = fmaf(p, w, 0.246640727f);
    p = fmaf(p, w, 1.50140941f);
  } else {
    w = __fsub_rn(sqrtf(w), 3.0f);
    p = -0.000200214257f;
    p = fmaf(p, w, 0.000100950558f);
    p = fmaf(p, w, 0.00134934322f);
    p = fmaf(p, w, -0.00367342844f);
    p = fmaf(p, w, 0.00573950773f);
    p = fmaf(p, w, -0.0076224613f);
    p = fmaf(p, w, 0.00943887047f);
    p = fmaf(p, w, 1.00167406f);
    p = fmaf(p, w, 2.83297682f);
  }
  return __fmul_rn(p, x);
}

__device__ __forceinline__ float noise_at(unsigned e){
  unsigned x0 = 0u, x1 = e;
  const unsigned k0 = 0u, k1 = 42u, k2 = 0u ^ 42u ^ 0x1BD11BDAu;
  x0 += k0; x1 += k1;
#define TFR(r) { x0 += x1; x1 = tf_rotl(x1, r); x1 ^= x0; }
  TFR(13) TFR(15) TFR(26) TFR(6)   x0 += k1; x1 += k2 + 1u;
  TFR(17) TFR(29) TFR(16) TFR(24)  x0 += k2; x1 += k0 + 2u;
  TFR(13) TFR(15) TFR(26) TFR(6)   x0 += k0; x1 += k1 + 3u;
  TFR(17) TFR(29) TFR(16) TFR(24)  x0 += k1; x1 += k2 + 4u;
  TFR(13) TFR(15) TFR(26) TFR(6)   x0 += k2; x1 += k0 + 5u;
#undef TFR
  unsigned bits = x0 ^ x1;
  float f = __uint_as_float((bits >> 9) | 0x3f800000u) - 1.0f;
  const float lo = -0.99999994f;
  float u = fmaf(f, 2.0f, lo);
  u = fmaxf(lo, u);
  float z = erfinv_xla_f32(u);
  float nrm = __fmul_rn(__uint_as_float(0x3FB504F3u), z);
  return __fmul_rn(nrm, 0.01f);
}

// u64-key max step via DPP (VALU domain, no LDS)
__device__ __forceinline__ unsigned long long dpp_max_u64(unsigned long long k, const int ctrl){
  int lo = (int)(unsigned)(k & 0xffffffffull);
  int hi = (int)(unsigned)(k >> 32);
  int slo, shi;
  switch (ctrl) {
    case 0x111: slo = __builtin_amdgcn_update_dpp(lo, lo, 0x111, 0xF, 0xF, false);
                shi = __builtin_amdgcn_update_dpp(hi, hi, 0x111, 0xF, 0xF, false); break;
    case 0x112: slo = __builtin_amdgcn_update_dpp(lo, lo, 0x112, 0xF, 0xF, false);
                shi = __builtin_amdgcn_update_dpp(hi, hi, 0x112, 0xF, 0xF, false); break;
    case 0x114: slo = __builtin_amdgcn_update_dpp(lo, lo, 0x114, 0xF, 0xF, false);
                shi = __builtin_amdgcn_update_dpp(hi, hi, 0x114, 0xF, 0xF, false); break;
    case 0x118: slo = __builtin_amdgcn_update_dpp(lo, lo, 0x118, 0xF, 0xF, false);
                shi = __builtin_amdgcn_update_dpp(hi, hi, 0x118, 0xF, 0xF, false); break;
    case 0x142: slo = __builtin_amdgcn_update_dpp(lo, lo, 0x142, 0xF, 0xF, false);
                shi = __builtin_amdgcn_update_dpp(hi, hi, 0x142, 0xF, 0xF, false); break;
    default:    slo = __builtin_amdgcn_update_dpp(lo, lo, 0x143, 0xF, 0xF, false);
                shi = __builtin_amdgcn_update_dpp(hi, hi, 0x143, 0xF, 0xF, false); break;
  }
  unsigned long long o = ((unsigned long long)(unsigned)shi << 32) | (unsigned)slo;
  return (o > k) ? o : k;
}

// ---------------- Kernel 1: FPS (512 thr / 2 waves per SIMD, DPP argmax, 1 barrier/iter) ----------------
__global__ __launch_bounds__(512, 1) void fps_kernel(const float* __restrict__ pin,
                                                     float* __restrict__ ptsO){
  const int b = blockIdx.x;
  const int t = threadIdx.x;
  const float* P = pin + (size_t)b * N_IN * 3;

  __shared__ float s_x[N_IN], s_y[N_IN], s_z[N_IN];
  __shared__ int   s_sel[M];
  __shared__ unsigned s_cand[2][8][2];   // [parity][wave][klo,khi]

  for (int i = t; i < N_IN; i += 512) {
    s_x[i] = P[i*3+0]; s_y[i] = P[i*3+1]; s_z[i] = P[i*3+2];
  }
  float px[16], py[16], pz[16], mind[16];
#pragma unroll
  for (int k = 0; k < 16; ++k) {
    int p = t + (k<<9);
    px[k] = P[p*3+0]; py[k] = P[p*3+1]; pz[k] = P[p*3+2];
    mind[k] = 1e10f;
  }
  if (t == 0) s_sel[0] = 0;
  float lx = P[0], ly = P[1], lz = P[2];
  __syncthreads();

  for (int i = 1; i < M; ++i) {
    float bv = -1.0f; int bi = 0x7fffffff;
#pragma unroll
    for (int k = 0; k < 16; ++k) {
      float dx = __fsub_rn(px[k], lx);
      float dy = __fsub_rn(py[k], ly);
      float dz = __fsub_rn(pz[k], lz);
      float d  = __fadd_rn(__fadd_rn(__fmul_rn(dx,dx), __fmul_rn(dy,dy)), __fmul_rn(dz,dz));
      float m  = fminf(mind[k], d);
      mind[k] = m;
      int idx  = t + (k<<9);
      if (m > bv) { bv = m; bi = idx; }   // k ascending => first-max per thread
    }
    unsigned long long key = ((unsigned long long)__float_as_uint(bv) << 32) | (unsigned)(~bi);
    key = dpp_max_u64(key, 0x111);
    key = dpp_max_u64(key, 0x112);
    key = dpp_max_u64(key, 0x114);
    key = dpp_max_u64(key, 0x118);
    key = dpp_max_u64(key, 0x142);
    key = dpp_max_u64(key, 0x143);      // lane 63 holds wave max
    int par = i & 1;
    if ((t & 63) == 63) {               // lane 63 stores its own regs (no readlane)
      s_cand[par][t>>6][0] = (unsigned)(key & 0xffffffffull);
      s_cand[par][t>>6][1] = (unsigned)(key >> 32);
    }
    __syncthreads();
    unsigned long long kb = ((unsigned long long)s_cand[par][0][1] << 32) | s_cand[par][0][0];
#pragma unroll
    for (int w2 = 1; w2 < 8; ++w2) {
      unsigned long long ko = ((unsigned long long)s_cand[par][w2][1] << 32) | s_cand[par][w2][0];
      if (ko > kb) kb = ko;
    }
    int bsel = (int)(~(unsigned)(kb & 0xffffffffull));
    if (t == 0) s_sel[i] = bsel;
    lx = s_x[bsel]; ly = s_y[bsel]; lz = s_z[bsel];
  }
  __syncthreads();

  for (int j = t; j < M; j += 512) {
    int sj = s_sel[j];
    float x = s_x[sj], y = s_y[sj], z = s_z[sj];
    float* o0 = ptsO + ((size_t)b*M2 + j)*3;
    float* o1 = o0 + (size_t)M*3;
    o0[0]=x; o0[1]=y; o0[2]=z;
    unsigned e0 = (unsigned)(b*M + j) * 3u;
    o1[0] = __fadd_rn(x, noise_at(e0+0u));
    o1[1] = __fadd_rn(y, noise_at(e0+1u));
    o1[2] = __fadd_rn(z, noise_at(e0+2u));
  }
}

// ---------------- math helpers ----------------
__device__ __forceinline__ float gelu_f(float x){
  return x * (erff(x / 1.41421356237f) + 1.0f) * 0.5f;
}
__device__ __forceinline__ float softplus_f(float x){
  return fmaxf(x, 0.0f) + log1pf(expf(-fabsf(x)));
}
__device__ __forceinline__ void eig3_sym(double a00,double a01,double a02,double a11,double a12,double a22,
                                         double& s0o, double& s1o, double& s2o){
  double p1 = a01*a01 + a02*a02 + a12*a12;
  double q  = (a00+a11+a22)/3.0;
  double b00=a00-q, b11=a11-q, b22=a22-q;
  double p2 = b00*b00+b11*b11+b22*b22 + 2.0*p1;
  double e0,e1,e2;
  if (p2 <= 0.0) { e0=e1=e2=q; }
  else {
    double p  = sqrt(p2/6.0);
    double ip = 1.0/p;
    double c00=b00*ip, c01=a01*ip, c02=a02*ip, c11=b11*ip, c12=a12*ip, c22=b22*ip;
    double detB = c00*(c11*c22-c12*c12) - c01*(c01*c22-c12*c02) + c02*(c01*c12-c11*c02);
    double r = 0.5*detB;
    r = fmin(1.0, fmax(-1.0, r));
    double phi = acos(r)/3.0;
    e0 = q + 2.0*p*cos(phi);
    e2 = q + 2.0*p*cos(phi + 2.0943951023931953);
    e1 = 3.0*q - e0 - e2;
  }
  double s0 = fabs(e0), s1 = fabs(e1), s2 = fabs(e2), t;
  if (s0 < s1){t=s0;s0=s1;s1=t;}
  if (s1 < s2){t=s1;s1=s2;s2=t;}
  if (s0 < s1){t=s0;s0=s1;s1=t;}
  s0o=s0; s1o=s1; s2o=s2;
}

// stable top-17 insert (d2 asc, scan order = idx asc on ties), shared-compare form
__device__ __forceinline__ void ins17(float d2, int j, float bd[17], int bix[17]){
  bool c[17];
#pragma unroll
  for (int k = 0; k < 17; ++k) c[k] = d2 < bd[k];
#pragma unroll
  for (int k = 16; k > 0; --k) {
    bd[k]  = c[k-1] ? bd[k-1] : (c[k] ? d2 : bd[k]);
    bix[k] = c[k-1] ? bix[k-1] : (c[k] ? j : bix[k]);
  }
  if (c[0]) { bd[0] = d2; bix[0] = j; }
}

// monotone map f32 -> u32 (order-preserving incl. negatives)
__device__ __forceinline__ unsigned fmono(float f){
  unsigned u = __float_as_uint(f);
  return (u & 0x80000000u) ? ~u : (u | 0x80000000u);
}

// ---------------- Kernel 2: chunked KNN top-17 (8 chunks x 32 rows) + u64 8-way merge ----------------
__global__ __launch_bounds__(256) void knn_select(const float* __restrict__ ptsG,
                                                  float* __restrict__ RO){
  const int b = blockIdx.x, tid = threadIdx.x;

  __shared__ __align__(16) unsigned char smem[35840];
  float4* sp = (float4*)smem;                                    // phase A: 1638*16 = 26208 B

  for (int i = tid; i < M2; i += 256) {
    const float* p = ptsG + ((size_t)b*M2 + i)*3;
    float x=p[0], y=p[1], z=p[2];
    float sq = __fadd_rn(__fadd_rn(__fmul_rn(x,x),__fmul_rn(y,y)),__fmul_rn(z,z));
    sp[i] = make_float4(x,y,z,sq);
  }
  __syncthreads();

  const int rl    = tid >> 3;
  const int chunk = tid & 7;
  const int row   = blockIdx.y*RPB + rl;
  const bool valid = row < M2;

  float4 me = sp[valid ? row : 0];
  const float px = me.x, py = me.y, pz = me.z, psq = me.w;

  float bd[17]; int bix[17];
#pragma unroll
  for (int k=0;k<17;++k){ bd[k]=3.4e38f; bix[k]=0x7fffffff; }

  const int j0 = chunk*CHLEN;
  const int j1 = (j0 + CHLEN < M2) ? (j0 + CHLEN) : M2;
  for (int j = j0; j < j1; j += 2) {
    float4 qa = sp[j];
    float4 qb = sp[j+1];
    float dota = fmaf(pz, qa.z, fmaf(py, qa.y, __fmul_rn(px, qa.x)));
    float d2a  = __fsub_rn(__fadd_rn(psq, qa.w), __fmul_rn(2.0f, dota));
    float dotb = fmaf(pz, qb.z, fmaf(py, qb.y, __fmul_rn(px, qb.x)));
    float d2b  = __fsub_rn(__fadd_rn(psq, qb.w), __fmul_rn(2.0f, dotb));
    if (fminf(d2a, d2b) < bd[16]) {
      if (d2a < bd[16]) ins17(d2a, j,   bd, bix);
      if (d2b < bd[16]) ins17(d2b, j+1, bd, bix);
    }
  }
  __syncthreads();   // sp dead; reuse smem for per-chunk lists

  unsigned long long* s_kid = (unsigned long long*)smem;         // 32*8*17*8 = 34816
  unsigned short*     s_nbr = (unsigned short*)(smem + 34816);   // 32*16*2   =  1024

  if (valid) {
    const int basel = (rl*NCH + chunk)*17;
#pragma unroll
    for (int k = 0; k < 17; ++k)
      s_kid[basel + k] = ((unsigned long long)fmono(bd[k]) << 32) | (unsigned)bix[k];
  }
  __syncthreads();

  if (chunk == 0 && valid) {
    int h0=0,h1=0,h2=0,h3=0,h4=0,h5=0,h6=0,h7=0;
    const int lb = rl*NCH*17;
    for (int e = 0; e < 17; ++e) {
      unsigned long long k0 = s_kid[lb        + h0];
      unsigned long long k1 = s_kid[lb + 17   + h1];
      unsigned long long k2 = s_kid[lb + 34   + h2];
      unsigned long long k3 = s_kid[lb + 51   + h3];
      unsigned long long k4 = s_kid[lb + 68   + h4];
      unsigned long long k5 = s_kid[lb + 85   + h5];
      unsigned long long k6 = s_kid[lb + 102  + h6];
      unsigned long long k7 = s_kid[lb + 119  + h7];
      unsigned long long bk = k0; int bc = 0;
      if (k1 < bk) { bk = k1; bc = 1; }
      if (k2 < bk) { bk = k2; bc = 2; }
      if (k3 < bk) { bk = k3; bc = 3; }
      if (k4 < bk) { bk = k4; bc = 4; }
      if (k5 < bk) { bk = k5; bc = 5; }
      if (k6 < bk) { bk = k6; bc = 6; }
      if (k7 < bk) { bk = k7; bc = 7; }
      h0 += (bc==0); h1 += (bc==1); h2 += (bc==2); h3 += (bc==3);
      h4 += (bc==4); h5 += (bc==5); h6 += (bc==6); h7 += (bc==7);
      if (e > 0) s_nbr[rl*16 + (e-1)] = (unsigned short)(bk & 0xffffu);  // entry 0 = self, dropped
    }
    uint* kout = (uint*)(RO + ((size_t)b*M2 + row)*9);
#pragma unroll
    for (int k = 0; k < 8; ++k)
      kout[k] = (uint)s_nbr[rl*16 + 2*k] | ((uint)s_nbr[rl*16 + 2*k + 1] << 16);
  }
}

// ---------------- Kernel 3: per-row geometry (validated) ----------------
__global__ __launch_bounds__(256) void geom_kernel(
    const float* __restrict__ ptsG,
    const float* __restrict__ rw1, const float* __restrict__ rb1,
    const float* __restrict__ rw2, const float* __restrict__ rb2,
    const float* __restrict__ sw1, const float* __restrict__ sb1,
    const float* __restrict__ sw2, const float* __restrict__ sb2,
    float* __restrict__ covO, float* __restrict__ RO, float* __restrict__ scO,
    float* __restrict__ linW, float* __restrict__ denW)
{
  const int tid = threadIdx.x;
  __shared__ float w_rw1[192], w_rb1[64], w_rw2[192], w_rb2[3];
  __shared__ float w_sw1[192], w_sb1[64], w_sw2[192], w_sb2[3];
  if (tid < 192) { w_rw1[tid]=rw1[tid]; w_rw2[tid]=rw2[tid]; w_sw1[tid]=sw1[tid]; w_sw2[tid]=sw2[tid]; }
  if (tid < 64) { w_rb1[tid]=rb1[tid]; w_sb1[tid]=sb1[tid]; }
  if (tid < 3)  { w_rb2[tid]=rb2[tid]; w_sb2[tid]=sb2[tid]; }
  __syncthreads();

  const int gid = blockIdx.x*256 + tid;
  if (gid >= BB*M2) return;
  const int b = gid / M2;
  const size_t base = (size_t)gid;

  const uint* kin = (const uint*)(RO + base*9);
  uint kw[8];
#pragma unroll
  for (int k = 0; k < 8; ++k) kw[k] = kin[k];
  asm volatile("" ::: "memory");

  int nidx[16];
#pragma unroll
  for (int k = 0; k < 8; ++k) { nidx[2*k] = (int)(kw[k] & 0xffffu); nidx[2*k+1] = (int)(kw[k] >> 16); }

  const float* meP = ptsG + base*3;
  const float px = meP[0], py = meP[1], pz = meP[2];
  const double pxd = (double)px, pyd = (double)py, pzd = (double)pz;

  float nx[16], ny[16], nz[16];
#pragma unroll
  for (int k = 0; k < 16; ++k) {
    const float* np = ptsG + ((size_t)b*M2 + nidx[k])*3;
    nx[k] = np[0]; ny[k] = np[1]; nz[k] = np[2];
  }

  float wcx=0.f, wcy=0.f, wcz=0.f;
#pragma unroll
  for (int k=0;k<16;++k){ wcx += nx[k]; wcy += ny[k]; wcz += nz[k]; }
  wcx *= 0.0625f; wcy *= 0.0625f; wcz *= 0.0625f;

  float aa0=0.f, aa1=0.f, aa2=0.f;
  for (int j = 0; j < 64; ++j) {
    float hp = __fadd_rn(__fadd_rn(__fadd_rn(__fmul_rn(wcx,w_rw1[j]), __fmul_rn(wcy,w_rw1[64+j])),
                                   __fmul_rn(wcz,w_rw1[128+j])), w_rb1[j]);
    float h = gelu_f(hp);
    aa0 += h*w_rw2[j*3+0]; aa1 += h*w_rw2[j*3+1]; aa2 += h*w_rw2[j*3+2];
  }
  aa0 += w_rb2[0]; aa1 += w_rb2[1]; aa2 += w_rb2[2];

  float angle = sqrtf(__fadd_rn(__fadd_rn(__fmul_rn(aa0,aa0),__fmul_rn(aa1,aa1)),__fmul_rn(aa2,aa2)));
  bool  tsml  = angle < 1e-4f;
  float sang  = tsml ? 0.0f : fminf(angle, 3.14f);
  float ax, ay, az;
  if (tsml) { ax=1.0f; ay=0.0f; az=0.0f; }
  else { float inv = angle + 1e-6f; ax = aa0/inv; ay = aa1/inv; az = aa2/inv; }

  float v0 = ax*sang, v1 = ay*sang, v2 = az*sang;
  float ang2 = sqrtf(__fadd_rn(__fadd_rn(__fmul_rn(v0,v0),__fmul_rn(v1,v1)),__fmul_rn(v2,v2)));
  float inv2 = ang2 + 1e-6f;
  float x = v0/inv2, y = v1/inv2, z = v2/inv2;
  float ca = cosf(ang2), sa = sinf(ang2), Cc = 1.0f - ca;
  float R00 = ca + x*x*Cc,   R01 = x*y*Cc - z*sa, R02 = x*z*Cc + y*sa;
  float R10 = y*x*Cc + z*sa, R11 = ca + y*y*Cc,   R12 = y*z*Cc - x*sa;
  float R20 = z*x*Cc - y*sa, R21 = z*y*Cc + x*sa, R22 = ca + z*z*Cc;

  float sp0=0.f, sp1=0.f, sp2=0.f;
  for (int j = 0; j < 64; ++j) {
    float hp = __fadd_rn(__fadd_rn(__fadd_rn(__fmul_rn(px,w_sw1[j]), __fmul_rn(py,w_sw1[64+j])),
                                   __fmul_rn(pz,w_sw1[128+j])), w_sb1[j]);
    float h = gelu_f(hp);
    sp0 += h*w_sw2[j*3+0]; sp1 += h*w_sw2[j*3+1]; sp2 += h*w_sw2[j*3+2];
  }
  sp0 += w_sb2[0]; sp1 += w_sb2[1]; sp2 += w_sb2[2];
  float sc0 = fminf(fmaxf(softplus_f(sp0), 0.01f), 0.5f);
  float sc1 = fminf(fmaxf(softplus_f(sp1), 0.01f), 0.5f);
  float sc2 = fminf(fmaxf(softplus_f(sp2), 0.01f), 0.5f);

  float s2x = sc0*sc0, s2y = sc1*sc1, s2z = sc2*sc2;
  float T00 = R00*s2x, T01 = R01*s2y, T02 = R02*s2z;
  float T10 = R10*s2x, T11 = R11*s2y, T12 = R12*s2z;
  float T20 = R20*s2x, T21 = R21*s2y, T22 = R22*s2z;
  float C00 = T00*R00 + T01*R01 + T02*R02;
  float C01 = T00*R10 + T01*R11 + T02*R12;
  float C02 = T00*R20 + T01*R21 + T02*R22;
  float C10 = T10*R00 + T11*R01 + T12*R02;
  float C11 = T10*R10 + T11*R11 + T12*R12;
  float C12 = T10*R20 + T11*R21 + T12*R22;
  float C20 = T20*R00 + T21*R01 + T22*R02;
  float C21 = T20*R10 + T21*R11 + T22*R12;
  float C22 = T20*R20 + T21*R21 + T22*R22;

  double n00=0.,n01=0.,n02=0.,n11=0.,n12=0.,n22=0.;
  int cnt = 0;
  const double R2 = 0.1*0.1;
#pragma unroll
  for (int k=0;k<16;++k){
    double cx = (double)nx[k] - pxd;
    double cy = (double)ny[k] - pyd;
    double cz = (double)nz[k] - pzd;
    n00 += cx*cx; n01 += cx*cy; n02 += cx*cz;
    n11 += cy*cy; n12 += cy*cz; n22 += cz*cz;
    double dd = cx*cx + cy*cy + cz*cz;
    if (dd < R2) cnt++;
  }
  const double inv15 = 15.0 + 1e-6;
  n00/=inv15; n01/=inv15; n02/=inv15; n11/=inv15; n12/=inv15; n22/=inv15;

  double sv0, sv1, sv2;
  eig3_sym(n00,n01,n02,n11,n12,n22, sv0, sv1, sv2);
  float lin = (float)(sv0 / (sv1 + sv2 + 1e-6));
  float den = (float)cnt / 16.0f;

  float* cO = covO + base*9;
  cO[0]=C00; cO[1]=C01; cO[2]=C02; cO[3]=C10; cO[4]=C11; cO[5]=C12; cO[6]=C20; cO[7]=C21; cO[8]=C22;
  float* rO = RO + base*9;
  rO[0]=R00; rO[1]=R01; rO[2]=R02; rO[3]=R10; rO[4]=R11; rO[5]=R12; rO[6]=R20; rO[7]=R21; rO[8]=R22;
  float* sO = scO + base*3;
  sO[0]=sc0; sO[1]=sc1; sO[2]=sc2;
  linW[base] = lin;
  denW[base] = den;
}

// ---------------- Kernel 4: per-batch min/max ----------------
__global__ __launch_bounds__(256) void minmax_k(const float* __restrict__ linW,
                                                const float* __restrict__ denW,
                                                float* __restrict__ mmW){
  const int b = blockIdx.x, t = threadIdx.x;
  float lmin=3.4e38f, lmax=-3.4e38f, dmin=3.4e38f, dmax=-3.4e38f;
  for (int i = t; i < M2; i += 256) {
    float l = linW[b*M2+i], d = denW[b*M2+i];
    lmin=fminf(lmin,l); lmax=fmaxf(lmax,l);
    dmin=fminf(dmin,d); dmax=fmaxf(dmax,d);
  }
#pragma unroll
  for (int off = 32; off > 0; off >>= 1) {
    lmin=fminf(lmin,__shfl_down(lmin,(unsigned)off));
    lmax=fmaxf(lmax,__shfl_down(lmax,(unsigned)off));
    dmin=fminf(dmin,__shfl_down(dmin,(unsigned)off));
    dmax=fmaxf(dmax,__shfl_down(dmax,(unsigned)off));
  }
  __shared__ float s[4][4];
  int w = t >> 6;
  if ((t & 63) == 0) { s[w][0]=lmin; s[w][1]=lmax; s[w][2]=dmin; s[w][3]=dmax; }
  __syncthreads();
  if (t == 0) {
    for (int i = 1; i < 4; ++i) {
      s[0][0]=fminf(s[0][0],s[i][0]); s[0][1]=fmaxf(s[0][1],s[i][1]);
      s[0][2]=fminf(s[0][2],s[i][2]); s[0][3]=fmaxf(s[0][3],s[i][3]);
    }
    mmW[b*4+0]=s[0][0]; mmW[b*4+1]=s[0][1]; mmW[b*4+2]=s[0][2]; mmW[b*4+3]=s[0][3];
  }
}

// ---------------- Kernel 5: opacity ----------------
__global__ void opacity_k(const float* __restrict__ linW, const float* __restrict__ denW,
                          const float* __restrict__ mmW, float* __restrict__ opO){
  int gid = blockIdx.x*blockDim.x + threadIdx.x;
  if (gid >= BB*M2) return;
  int b = gid / M2;
  float lmin=mmW[b*4+0], lmax=mmW[b*4+1], dmin=mmW[b*4+2], dmax=mmW[b*4+3];
  float nl = (linW[gid]-lmin) / ((lmax-lmin) + 1e-6f);
  float nd = (denW[gid]-dmin) / ((dmax-dmin) + 1e-6f);
  float comb = nl * powf(nd, 0.45f);
  opO[gid] = fminf(fmaxf(comb, 0.05f), 0.95f);
}

// ---------------- launch ----------------
extern "C" void kernel_launch(void* const* d_in, const int* in_sizes, int n_in,
                              void* d_out, int out_size, void* d_ws, size_t ws_size,
                              hipStream_t stream) {
  const float* pin = (const float*)d_in[0];
  const float* rw1 = (const float*)d_in[1];
  const float* rb1 = (const float*)d_in[2];
  const float* rw2 = (const float*)d_in[3];
  const float* rb2 = (const float*)d_in[4];
  const float* sw1 = (const float*)d_in[5];
  const float* sb1 = (const float*)d_in[6];
  const float* sw2 = (const float*)d_in[7];
  const float* sb2 = (const float*)d_in[8];

  float* out  = (float*)d_out;
  float* ptsO = out;                                  // B*M2*3
  float* covO = ptsO + (size_t)BB*M2*3;               // B*M2*9
  float* opO  = covO + (size_t)BB*M2*9;               // B*M2
  float* RO   = opO  + (size_t)BB*M2;                 // B*M2*9
  float* scO  = RO   + (size_t)BB*M2*9;               // B*M2*3

  float* linW = (float*)d_ws + (size_t)BB*M;          // B*M2
  float* denW = linW + (size_t)BB*M2;                 // B*M2
  float* mmW  = denW + (size_t)BB*M2;                 // B*4

  fps_kernel<<<BB, 512, 0, stream>>>(pin, ptsO);
  dim3 g2(BB, (M2 + RPB - 1)/RPB);
  knn_select<<<g2, 256, 0, stream>>>(ptsO, RO);
  geom_kernel<<<(BB*M2 + 255)/256, 256, 0, stream>>>(ptsO, rw1, rb1, rw2, rb2, sw1, sb1, sw2, sb2,
                                                     covO, RO, scO, linW, denW);
  minmax_k<<<BB, 256, 0, stream>>>(linW, denW, mmW);
  opacity_k<<<(BB*M2 + 255)/256, 256, 0, stream>>>(linW, denW, mmW, opO);
}